// Round 12
// baseline (366.354 us; speedup 1.0000x reference)
//
#include <hip/hip_runtime.h>
#include <hip/hip_bf16.h>
#include <stdint.h>

// Problem constants (B, N, E, D) = (32, 4096, 8192, 128); all float io fp32.
// R11 (318.7us verified): CSR builder + fused gather/gemm 139us (MfmaUtil
// 7.1%, VALUBusy 27%, hbm 1.24TB/s, occ ~20%). ~167us structure-invariant
// harness overhead (held across 4/3/2 launches).
// R12/R13 (FAILED post-timing, absmax 4.23): raw s_barrier pipeline raced
// intermittently (m152 failure mode; asm lgkmcnt had no "memory" clobber,
// s_barrier is not an IR memory fence). Reverted.
// R14: same drain-removal goal, race-free mechanism. Keep __syncthreads
// (standard semantics) + R11-verified dataflow; make the k-loop STORE-FREE:
// per-tile GRU math kept in-loop (VALU under MFMA shadow) but results parked
// in obuf[8][4] (32 VGPR, static idx via full unroll, rule #20); all stores
// issued after the last barrier. In-loop vmem = issue loads only, consumed
// by finish before each barrier -> vmcnt ~0 at every __syncthreads; the
// per-tile store-ack drain (~300-500cyc x 7) disappears.
#define BB 32
#define NN 4096
#define EE 8192
#define DD 128
#define MM (BB * NN)        // 131072 rows
#define THREE_D (3 * DD)    // 384

typedef __bf16 bf16x8 __attribute__((ext_vector_type(8)));
typedef __bf16 bf16x4 __attribute__((ext_vector_type(4)));
typedef float  f32x4  __attribute__((ext_vector_type(4)));

// ws layout
#define WT_OFF   0                       // 192 KiB bf16 [mat][col][k]
#define OFFC_OFF ((size_t)1 << 20)       // int2 per node (off, cnt), 1 MiB
#define CSR_OFF  ((size_t)2 << 20)       // BB*EE edge ids + 8 pad, ~1 MiB

// ---------------------------------------------------------------------------
// Kernel 1: blocks 0..31: per-batch CSR build (LDS histogram + prefix +
// scatter). Blocks 32..415: weight transpose fp32->bf16 (D,3D)->(3D,D).
// (verified R11)
// ---------------------------------------------------------------------------
__global__ __launch_bounds__(256)
void build_tables(const float* __restrict__ w0,
                  const float* __restrict__ w1,
                  const int* __restrict__ conn,
                  __bf16* __restrict__ wt,
                  int2* __restrict__ offcnt,
                  int* __restrict__ csr) {
    if (blockIdx.x >= BB) {
        int tid = (blockIdx.x - BB) * 256 + threadIdx.x;   // 0 .. 98303
        int mat = tid / (THREE_D * DD);
        int rem = tid % (THREE_D * DD);
        int col = rem / DD;
        int k   = rem % DD;
        const float* src = mat ? w1 : w0;
        wt[tid] = (__bf16)src[k * THREE_D + col];
        return;
    }
    __shared__ int tgtL[EE];               // 32 KiB: this batch's targets
    __shared__ int hist[NN];               // 16 KiB: histogram, then cursors
    __shared__ int part[256];
    const int b   = blockIdx.x;
    const int tid = threadIdx.x;
    const int2* c2 = (const int2*)conn + (size_t)b * EE;

    for (int k = 0; k < EE / 256; ++k) {   // A: load targets (coalesced)
        int e = k * 256 + tid;
        tgtL[e] = c2[e].y;
    }
    for (int n = tid; n < NN; n += 256) hist[n] = 0;
    __syncthreads();
    for (int k = 0; k < EE / 256; ++k)     // B: LDS histogram
        atomicAdd(&hist[tgtL[k * 256 + tid]], 1);
    __syncthreads();

    // C: exclusive prefix. Thread t owns 16 counters; scan 256 partials.
    const int c0 = tid * 16;
    int s = 0;
    for (int i = 0; i < 16; ++i) s += hist[c0 + i];
    part[tid] = s;
    __syncthreads();
    for (int d = 1; d < 256; d <<= 1) {    // Hillis-Steele inclusive
        int v = (tid >= d) ? part[tid - d] : 0;
        __syncthreads();
        part[tid] += v;
        __syncthreads();
    }
    int run = part[tid] - s;               // exclusive base of my chunk
    for (int i = 0; i < 16; ++i) {
        int c = hist[c0 + i];
        offcnt[(size_t)b * NN + c0 + i] = (int2){b * EE + run, c};
        hist[c0 + i] = run;                // cursor (batch-local offset)
        run += c;
    }
    __syncthreads();

    for (int k = 0; k < EE / 256; ++k) {   // D: scatter ids (32KB window)
        int e = k * 256 + tid;
        int t = tgtL[e];
        int pos = atomicAdd(&hist[t], 1);
        csr[(size_t)b * EE + pos] = b * EE + e;
    }
}

// ---------------------------------------------------------------------------
// Kernel 2: fused gather + dual-GEMM + GRU gates, store-free k-loop.
// 512 thr = 8 waves; wave w owns gate-col group g=w. Per tile t:
//   __syncthreads (drains ~nothing: no stores in loop, loads consumed)
//   issue(t+1): 4 predicated msg f32x4 + 1 h f32x4 per thread (slot
//     rb=tid>>5, c4=(tid&31)*4); full MFMA phase of latency cover
//   MFMA(t) from LDS[cur]; finish(t+1) -> LDS[cur^1]; GRU math -> obuf
// After loop: 32 coalesced stores per thread from obuf.
// MFMA layouts (gfx950, verified): A[m=lane&15][k=quad*8+j],
// B[k=quad*8+j][n=lane&15], C/D: col=lane&15, row=quad*4+reg.
// ---------------------------------------------------------------------------
#define TPB_GEMM 8   // 16-row tiles per block; 128 rows/block -> 1024 blocks
#define AGP 136      // padded agg LDS row (bf16 elems; 272B)
#define HP  132      // padded h   LDS row (f32 elems; 528B)

__launch_bounds__(512, 2)
__global__ void gru_gemm_fused(const float* __restrict__ messages,
                               const int2* __restrict__ offcnt,
                               const int* __restrict__ csr,
                               const float* __restrict__ h_in,
                               const __bf16* __restrict__ wt,
                               const float* __restrict__ bias,
                               float* __restrict__ out) {
    const int tid  = threadIdx.x;
    const int wave = tid >> 6;                         // = gate col group g
    const int lane = tid & 63;
    const int quad = lane >> 4;
    const int l16  = lane & 15;

    __shared__ __bf16 aT[2][16 * AGP];                 // 2 x 4.25 KiB
    __shared__ float  hT[2][16 * HP];                  // 2 x 8.25 KiB
    __shared__ int    idsL[128][8];                    // 4 KiB
    __shared__ int    cntL[128];
    __shared__ int    baseL[128];

    // B fragments [p][m][ko]: wt[(m*384+p*128+g*16+l16)*128 + ko*32+quad*8]
    bf16x8 bfrag[3][2][4];
    for (int p = 0; p < 3; ++p)
        for (int m = 0; m < 2; ++m)
            for (int ko = 0; ko < 4; ++ko)
                bfrag[p][m][ko] = *(const bf16x8*)(wt
                    + ((size_t)(m * THREE_D + p * 128 + wave * 16 + l16)) * DD
                    + ko * 32 + quad * 8);

    const int j = wave * 16 + l16;                     // gate index 0..127
    const float b0z = bias[j];
    const float b0r = bias[DD + j];
    const float b0h = bias[2 * DD + j];
    const float b1z = bias[THREE_D + j];
    const float b1r = bias[THREE_D + DD + j];
    const float b1h = bias[THREE_D + 2 * DD + j];

    const int tile0 = blockIdx.x * TPB_GEMM;

    // prologue: stage this block's 128 nodes' (base, cnt, ids[0..7]) in LDS
    if (tid < 128) {
        int2 oc = offcnt[(size_t)blockIdx.x * 128 + tid];
        baseL[tid] = oc.x;
        cntL[tid]  = oc.y;
        #pragma unroll
        for (int i = 0; i < 8; ++i)                    // speculative (padded)
            idsL[tid][i] = csr[(size_t)oc.x + i];
    }

    // ---- per-thread staging slot: row rb, 4-float chunk c4 ----
    const int rb = tid >> 5;                           // row in tile, 0..15
    const int c4 = (tid & 31) * 4;                     // chunk offset 0..124
    int cnt = 0, base_ = 0;
    f32x4 ma[4];                                       // batch-1 msg loads
    f32x4 sh;                                          // h chunk

    auto issue = [&](int t) {                          // t = tile in block
        int rbb = t * 16 + rb;
        cnt   = cntL[rbb];
        base_ = baseL[rbb];
        int e0 = (0 < cnt) ? idsL[rbb][0] : 0;
        int e1 = (1 < cnt) ? idsL[rbb][1] : 0;
        int e2 = (2 < cnt) ? idsL[rbb][2] : 0;
        int e3 = (3 < cnt) ? idsL[rbb][3] : 0;
        ma[0] = *(const f32x4*)(messages + (size_t)e0 * DD + c4);
        ma[1] = *(const f32x4*)(messages + (size_t)e1 * DD + c4);
        ma[2] = *(const f32x4*)(messages + (size_t)e2 * DD + c4);
        ma[3] = *(const f32x4*)(messages + (size_t)e3 * DD + c4);
        sh = *(const f32x4*)(h_in + (size_t)(tile0 + t) * 2048 + tid * 4);
    };
    auto finish = [&](int t, int bf) {
        int rbb = t * 16 + rb;
        f32x4 s0 = (f32x4){0.f, 0.f, 0.f, 0.f};
        #pragma unroll
        for (int i = 0; i < 4; ++i)
            if (i < cnt) s0 += ma[i];
        if (cnt > 4) {                                 // ~5% of rows
            #pragma unroll
            for (int i = 4; i < 8; ++i) {
                int e = (i < cnt) ? idsL[rbb][i] : 0;
                f32x4 v = *(const f32x4*)(messages + (size_t)e * DD + c4);
                if (i < cnt) s0 += v;
            }
            for (int i = 8; i < cnt; ++i) {            // ultra-rare tail
                int e = csr[(size_t)base_ + i];
                s0 += *(const f32x4*)(messages + (size_t)e * DD + c4);
            }
        }
        bf16x4 o;
        #pragma unroll
        for (int q = 0; q < 4; ++q) o[q] = (__bf16)s0[q];
        *(bf16x4*)&aT[bf][rb * AGP + c4] = o;          // 8B ds_write
        *(f32x4*)&hT[bf][rb * HP + c4] = sh;           // 16B ds_write
    };

    __syncthreads();                                   // idsL/cntL ready
    issue(0);
    finish(0, 0);                                      // cold stall once

    float obuf[TPB_GEMM][4];                           // deferred outputs
    int cur = 0;
    #pragma unroll
    for (int t = 0; t < TPB_GEMM; ++t) {
        __syncthreads();                               // buf staged; ~no vmem
        if (t + 1 < TPB_GEMM) issue(t + 1);            // full tile of cover

        const __bf16* aTc = aT[cur];
        const float*  hTc = hT[cur];

        f32x4 acc[3][2];                               // [part z/r/h][mat]
        for (int p = 0; p < 3; ++p)
            for (int m = 0; m < 2; ++m)
                acc[p][m] = (f32x4){0.f, 0.f, 0.f, 0.f};

        for (int ko = 0; ko < 4; ++ko) {
            bf16x8 af = *(const bf16x8*)&aTc[l16 * AGP + ko * 32 + quad * 8];
            f32x4 h0 = *(const f32x4*)&hTc[l16 * HP + ko * 32 + quad * 8];
            f32x4 h1 = *(const f32x4*)&hTc[l16 * HP + ko * 32 + quad * 8 + 4];
            bf16x8 hg;
            for (int i = 0; i < 4; ++i) {
                hg[i]     = (__bf16)h0[i];
                hg[i + 4] = (__bf16)h1[i];
            }
            for (int p = 0; p < 3; ++p) {
                acc[p][0] = __builtin_amdgcn_mfma_f32_16x16x32_bf16(
                    af, bfrag[p][0][ko], acc[p][0], 0, 0, 0);
                acc[p][1] = __builtin_amdgcn_mfma_f32_16x16x32_bf16(
                    hg, bfrag[p][1][ko], acc[p][1], 0, 0, 0);
            }
        }

        if (t + 1 < TPB_GEMM) finish(t + 1, cur ^ 1);  // consume + ds_write

        #pragma unroll
        for (int rr = 0; rr < 4; ++rr) {               // GRU math, no stores
            int rl = quad * 4 + rr;                    // row within tile
            float xz  = acc[0][0][rr] + b0z;
            float rz  = acc[0][1][rr] + b1z;
            float xr  = acc[1][0][rr] + b0r;
            float rrg = acc[1][1][rr] + b1r;
            float xh  = acc[2][0][rr] + b0h;
            float rh  = acc[2][1][rr] + b1h;
            float z   = 1.f / (1.f + __expf(-(xz + rz)));
            float rg  = 1.f / (1.f + __expf(-(xr + rrg)));
            float pre = xh + rg * rh;
            float hh  = 2.f / (1.f + __expf(-2.f * pre)) - 1.f;  // tanh
            float hold = hTc[rl * HP + j];             // fp32 h from LDS
            obuf[t][rr] = z * hold + (1.f - z) * hh;
        }
        cur ^= 1;
    }

    // deferred epilogue: 32 coalesced stores per thread
    #pragma unroll
    for (int t = 0; t < TPB_GEMM; ++t) {
        #pragma unroll
        for (int rr = 0; rr < 4; ++rr) {
            int row = (tile0 + t) * 16 + quad * 4 + rr;
            out[(size_t)row * DD + j] = obuf[t][rr];
        }
    }
}

// ---------------------------------------------------------------------------
extern "C" void kernel_launch(void* const* d_in, const int* in_sizes, int n_in,
                              void* d_out, int out_size, void* d_ws, size_t ws_size,
                              hipStream_t stream) {
    const float* atom_state = (const float*)d_in[0];
    const float* messages   = (const float*)d_in[1];
    const int*   conn       = (const int*)d_in[2];
    const float* w0         = (const float*)d_in[3];
    const float* w1         = (const float*)d_in[4];
    const float* bias       = (const float*)d_in[5];
    float* out = (float*)d_out;

    __bf16* wt     = (__bf16*)((char*)d_ws + WT_OFF);
    int2*   offcnt = (int2*)((char*)d_ws + OFFC_OFF);
    int*    csr    = (int*)((char*)d_ws + CSR_OFF);

    build_tables<<<BB + (2 * THREE_D * DD) / 256, 256, 0, stream>>>(
        w0, w1, conn, wt, offcnt, csr);
    gru_gemm_fused<<<MM / (16 * TPB_GEMM), 512, 0, stream>>>(
        messages, offcnt, csr, atom_state, wt, bias, out);
}